// Round 1
// baseline (504.250 us; speedup 1.0000x reference)
//
#include <hip/hip_runtime.h>
#include <math.h>

#define N_  2048
#define IN_ 400
#define C_  200
#define H_  256
#define M_  128
#define D_  8

// ---------------- q = x[:, :200] + x[:, 200:] ----------------
__global__ void q_kernel(const float* __restrict__ x, float* __restrict__ q) {
    int idx = blockIdx.x * 256 + threadIdx.x;
    if (idx >= N_ * C_) return;
    int n = idx / C_, c = idx % C_;
    q[idx] = x[n * IN_ + c] + x[n * IN_ + C_ + c];
}

// ---------------- generic NT GEMM: C[m,n] = act(sum_k A[m,k]*B[n,k] + bias[n]) ----
// A: M x K row-major (lda), B: N x K row-major (ldb)  -> row-dot-row
template<int BM, int BN, int BK, int TM, int TN, int ACT>
__global__ __launch_bounds__(256) void gemm_nt(
    const float* __restrict__ A, int lda,
    const float* __restrict__ B, int ldb,
    const float* __restrict__ bias,
    float* __restrict__ C, int ldc,
    int M, int N, int K)
{
    __shared__ float As[BK][BM + 1];
    __shared__ float Bs[BK][BN + 1];
    const int tid = threadIdx.x;
    const int tx = tid % (BN / TN);
    const int ty = tid / (BN / TN);
    const int m0 = blockIdx.y * BM;
    const int n0 = blockIdx.x * BN;

    float acc[TM][TN];
#pragma unroll
    for (int i = 0; i < TM; i++)
#pragma unroll
        for (int j = 0; j < TN; j++) acc[i][j] = 0.f;

    const int LA = BM * BK / 256;
    const int LB = BN * BK / 256;

    for (int k0 = 0; k0 < K; k0 += BK) {
#pragma unroll
        for (int j = 0; j < LA; j++) {
            int idx = j * 256 + tid;
            int i = idx / BK, kk = idx % BK;
            int kg = k0 + kk;
            As[kk][i] = (kg < K) ? A[(size_t)(m0 + i) * lda + kg] : 0.f;
        }
#pragma unroll
        for (int j = 0; j < LB; j++) {
            int idx = j * 256 + tid;
            int i = idx / BK, kk = idx % BK;
            int kg = k0 + kk;
            Bs[kk][i] = (kg < K) ? B[(size_t)(n0 + i) * ldb + kg] : 0.f;
        }
        __syncthreads();
#pragma unroll
        for (int kk = 0; kk < BK; kk++) {
            float a[TM], b[TN];
#pragma unroll
            for (int i = 0; i < TM; i++) a[i] = As[kk][ty * TM + i];
#pragma unroll
            for (int j = 0; j < TN; j++) b[j] = Bs[kk][tx * TN + j];
#pragma unroll
            for (int i = 0; i < TM; i++)
#pragma unroll
                for (int j = 0; j < TN; j++)
                    acc[i][j] = fmaf(a[i], b[j], acc[i][j]);
        }
        __syncthreads();
    }

#pragma unroll
    for (int i = 0; i < TM; i++) {
        int m = m0 + ty * TM + i;
#pragma unroll
        for (int j = 0; j < TN; j++) {
            int n = n0 + tx * TN + j;
            float val = acc[i][j];
            if (bias) val += bias[n];
            if (ACT == 1) val = tanhf(val);
            C[(size_t)m * ldc + n] = val;
        }
    }
}

// ---------------- softmax over rows of 128 (w) ----------------
__global__ void softmax128_kernel(float* __restrict__ w) {
    int n = blockIdx.x;
    int t = threadIdx.x;  // 64
    float v0 = w[n * M_ + t], v1 = w[n * M_ + 64 + t];
    float mx = fmaxf(v0, v1);
#pragma unroll
    for (int off = 32; off; off >>= 1) mx = fmaxf(mx, __shfl_xor(mx, off));
    float e0 = expf(v0 - mx), e1 = expf(v1 - mx);
    float s = e0 + e1;
#pragma unroll
    for (int off = 32; off; off >>= 1) s += __shfl_xor(s, off);
    float inv = 1.f / s;
    w[n * M_ + t] = e0 * inv;
    w[n * M_ + 64 + t] = e1 * inv;
}

// ---------------- w2 = softmax(k @ kw2_w.T + kw2_b) over D=8 ----------------
__global__ void w2_kernel(const float* __restrict__ k, const float* __restrict__ kw2_w,
                          const float* __restrict__ kw2_b, float* __restrict__ w2) {
    int t = threadIdx.x;               // 64 = 8 samples x 8 experts
    int n = blockIdx.x * 8 + (t >> 3);
    int d = t & 7;
    const float* kr = k + (size_t)n * H_;
    const float* wr = kw2_w + (size_t)d * H_;
    float acc = kw2_b[d];
    for (int h = 0; h < H_; h += 4)
        acc += kr[h] * wr[h] + kr[h + 1] * wr[h + 1] + kr[h + 2] * wr[h + 2] + kr[h + 3] * wr[h + 3];
    float mx = acc;
#pragma unroll
    for (int off = 1; off < 8; off <<= 1) mx = fmaxf(mx, __shfl_xor(mx, off));
    float e = expf(acc - mx);
    float s = e;
#pragma unroll
    for (int off = 1; off < 8; off <<= 1) s += __shfl_xor(s, off);
    w2[(size_t)n * D_ + d] = e / s;
}

// ---------------- gate: out = act(sum_d w2[n,d]*(t[n,d*H+o] + bias[d,o])) ----------------
template<int ACT>  // 0 = sigmoid, 1 = tanh
__global__ void gate_kernel(const float* __restrict__ t, const float* __restrict__ w2,
                            const float* __restrict__ bias, float* __restrict__ out) {
    int idx = blockIdx.x * 256 + threadIdx.x;  // N*H
    int n = idx >> 8;
    int o = idx & 255;
    const float* w2r = w2 + (size_t)n * D_;
    float acc = 0.f;
#pragma unroll
    for (int d = 0; d < D_; d++)
        acc += w2r[d] * (t[(size_t)n * (D_ * H_) + d * H_ + o] + bias[d * H_ + o]);
    out[idx] = (ACT == 0) ? 1.f / (1.f + expf(-acc)) : tanhf(acc);
}

// ---------------- fused memory pass: r = sum_m mem*w ; mem_out = mem*(1-w*e)+w*a ----
__global__ __launch_bounds__(256) void mem_kernel(
    const float* __restrict__ mem_in, const float* __restrict__ w,
    const float* __restrict__ e, const float* __restrict__ a,
    float* __restrict__ mem_out, float* __restrict__ r)
{
    __shared__ float wl[M_];
    int n = blockIdx.x;
    int t = threadIdx.x;
    if (t < M_) wl[t] = w[(size_t)n * M_ + t];
    __syncthreads();
    int wave = t >> 6, lane = t & 63;
    float w0 = wl[lane * 2], w1 = wl[lane * 2 + 1];
    const float2* min2 = (const float2*)(mem_in + (size_t)n * H_ * M_);
    float2* mout2 = (float2*)(mem_out + (size_t)n * H_ * M_);
    for (int h = wave; h < H_; h += 4) {
        float2 mv = min2[h * 64 + lane];
        float eh = e[(size_t)n * H_ + h], ah = a[(size_t)n * H_ + h];
        float2 nv;
        nv.x = mv.x * (1.f - w0 * eh) + w0 * ah;
        nv.y = mv.y * (1.f - w1 * eh) + w1 * ah;
        mout2[h * 64 + lane] = nv;
        float racc = mv.x * w0 + mv.y * w1;
#pragma unroll
        for (int off = 32; off; off >>= 1) racc += __shfl_xor(racc, off);
        if (lane == 0) r[(size_t)n * H_ + h] = racc;
    }
}

// ---------------- kr = concat(k, r) ----------------
__global__ void concat_kernel(const float* __restrict__ k, const float* __restrict__ r,
                              float* __restrict__ kr) {
    int idx = blockIdx.x * 256 + threadIdx.x;
    int n = idx >> 9, c = idx & 511;
    kr[idx] = (c < H_) ? k[(size_t)n * H_ + c] : r[(size_t)n * H_ + c - H_];
}

// ---------------- y[n] = f[n,:] . out_w + out_b ----------------
__global__ void y_kernel(const float* __restrict__ f, const float* __restrict__ out_w,
                         const float* __restrict__ out_b, float* __restrict__ y) {
    int n = blockIdx.x, t = threadIdx.x;  // 64
    float acc = 0.f;
#pragma unroll
    for (int j = 0; j < 4; j++) acc += f[(size_t)n * H_ + t + j * 64] * out_w[t + j * 64];
#pragma unroll
    for (int off = 32; off; off >>= 1) acc += __shfl_xor(acc, off);
    if (t == 0) y[n] = acc + out_b[0];
}

extern "C" void kernel_launch(void* const* d_in, const int* in_sizes, int n_in,
                              void* d_out, int out_size, void* d_ws, size_t ws_size,
                              hipStream_t stream) {
    const float* x      = (const float*)d_in[0];
    const float* mem_in = (const float*)d_in[1];
    const float* ke_w   = (const float*)d_in[2];
    const float* ke_b   = (const float*)d_in[3];
    const float* km_w   = (const float*)d_in[4];
    const float* km_b   = (const float*)d_in[5];
    const float* kw2_w  = (const float*)d_in[6];
    const float* kw2_b  = (const float*)d_in[7];
    const float* sum_w  = (const float*)d_in[8];
    const float* sum_b  = (const float*)d_in[9];
    const float* out_w  = (const float*)d_in[10];
    const float* out_b  = (const float*)d_in[11];
    const float* ve_w   = (const float*)d_in[12];
    const float* ve_b   = (const float*)d_in[13];
    const float* er_w   = (const float*)d_in[14];
    const float* er_b   = (const float*)d_in[15];
    const float* ad_w   = (const float*)d_in[16];
    const float* ad_b   = (const float*)d_in[17];

    float* y_out   = (float*)d_out;
    float* mem_out = (float*)d_out + N_;  // y (2048) then memory

    float* ws = (float*)d_ws;
    float* q    = ws;                   // N*C          = 409600
    float* kb   = q    + (size_t)N_ * C_;        // N*H = 524288
    float* w    = kb   + (size_t)N_ * H_;        // N*M = 262144
    float* w2   = w    + (size_t)N_ * M_;        // N*D = 16384
    float* v    = w2   + (size_t)N_ * D_;        // N*H
    float* tbuf = v    + (size_t)N_ * H_;        // N*(D*H) = 4194304
    float* e    = tbuf + (size_t)N_ * D_ * H_;   // N*H
    float* a    = e    + (size_t)N_ * H_;        // N*H
    float* r    = a    + (size_t)N_ * H_;        // N*H
    float* kr   = r    + (size_t)N_ * H_;        // N*2H = 1048576
    float* f    = kr   + (size_t)N_ * 2 * H_;    // N*H

    // 1. q
    q_kernel<<<(N_ * C_ + 255) / 256, 256, 0, stream>>>(x, q);
    // 2. k = q @ ke_w.T + ke_b   (M=2048, N=256, K=200)
    gemm_nt<64, 64, 16, 4, 4, 0><<<dim3(H_ / 64, N_ / 64), 256, 0, stream>>>(
        q, C_, ke_w, C_, ke_b, kb, H_, N_, H_, C_);
    // 3. w logits = k @ km_w.T + km_b  (N=128, K=256)
    gemm_nt<64, 64, 16, 4, 4, 0><<<dim3(M_ / 64, N_ / 64), 256, 0, stream>>>(
        kb, H_, km_w, H_, km_b, w, M_, N_, M_, H_);
    // 4. softmax rows of 128
    softmax128_kernel<<<N_, 64, 0, stream>>>(w);
    // 5. w2 logits + softmax over D=8
    w2_kernel<<<N_ / 8, 64, 0, stream>>>(kb, kw2_w, kw2_b, w2);
    // 6. v = x @ ve_w.T + ve_b  (K=400)
    gemm_nt<64, 64, 16, 4, 4, 0><<<dim3(H_ / 64, N_ / 64), 256, 0, stream>>>(
        x, IN_, ve_w, IN_, ve_b, v, H_, N_, H_, IN_);
    // 7. t_er = v @ er_w_flat.T  (M=2048, N=2048, K=256)
    gemm_nt<128, 128, 16, 8, 8, 0><<<dim3((D_ * H_) / 128, N_ / 128), 256, 0, stream>>>(
        v, H_, er_w, H_, nullptr, tbuf, D_ * H_, N_, D_ * H_, H_);
    // 8. e = sigmoid(sum_d w2*(t+er_b))
    gate_kernel<0><<<(N_ * H_) / 256, 256, 0, stream>>>(tbuf, w2, er_b, e);
    // 9. t_ad = v @ ad_w_flat.T
    gemm_nt<128, 128, 16, 8, 8, 0><<<dim3((D_ * H_) / 128, N_ / 128), 256, 0, stream>>>(
        v, H_, ad_w, H_, nullptr, tbuf, D_ * H_, N_, D_ * H_, H_);
    // 10. a = tanh(sum_d w2*(t+ad_b))
    gate_kernel<1><<<(N_ * H_) / 256, 256, 0, stream>>>(tbuf, w2, ad_b, a);
    // 11. fused memory read + update
    mem_kernel<<<N_, 256, 0, stream>>>(mem_in, w, e, a, mem_out, r);
    // 12. kr = [k, r]
    concat_kernel<<<(N_ * 2 * H_) / 256, 256, 0, stream>>>(kb, r, kr);
    // 13. f = tanh(kr @ sum_w.T + sum_b)  (K=512)
    gemm_nt<64, 64, 16, 4, 4, 1><<<dim3(H_ / 64, N_ / 64), 256, 0, stream>>>(
        kr, 2 * H_, sum_w, 2 * H_, sum_b, f, H_, N_, H_, 2 * H_);
    // 14. y
    y_kernel<<<N_, 64, 0, stream>>>(f, out_w, out_b, y_out);
}

// Round 2
// 363.937 us; speedup vs baseline: 1.3855x; 1.3855x over previous
//
#include <hip/hip_runtime.h>
#include <math.h>

#define N_  2048
#define IN_ 400
#define C_  200
#define H_  256
#define M_  128
#define D_  8

typedef __bf16 bf16x8 __attribute__((ext_vector_type(8)));
typedef float  f32x4  __attribute__((ext_vector_type(4)));

__device__ __forceinline__ ushort f2bf(float x) {
    __bf16 b = (__bf16)x;
    return __builtin_bit_cast(ushort, b);
}

// ---------------- q = x[:, :200] + x[:, 200:] ----------------
__global__ void q_kernel(const float* __restrict__ x, float* __restrict__ q) {
    int idx = blockIdx.x * 256 + threadIdx.x;
    if (idx >= N_ * C_) return;
    int n = idx / C_, c = idx % C_;
    q[idx] = x[n * IN_ + c] + x[n * IN_ + C_ + c];
}

// ---------------- generic NT GEMM (f32): C[m,n] = act(sum_k A[m,k]*B[n,k] + bias[n]) ----
// OUTBF: 0 = f32 out, 1 = bf16 (ushort) out
template<int BM, int BN, int BK, int TM, int TN, int ACT, int OUTBF>
__global__ __launch_bounds__(256) void gemm_nt(
    const float* __restrict__ A, int lda,
    const float* __restrict__ B, int ldb,
    const float* __restrict__ bias,
    void* __restrict__ Cv, int ldc,
    int M, int N, int K)
{
    __shared__ float As[BK][BM + 1];
    __shared__ float Bs[BK][BN + 1];
    const int tid = threadIdx.x;
    const int tx = tid % (BN / TN);
    const int ty = tid / (BN / TN);
    const int m0 = blockIdx.y * BM;
    const int n0 = blockIdx.x * BN;

    float acc[TM][TN];
#pragma unroll
    for (int i = 0; i < TM; i++)
#pragma unroll
        for (int j = 0; j < TN; j++) acc[i][j] = 0.f;

    const int LA = BM * BK / 256;
    const int LB = BN * BK / 256;

    for (int k0 = 0; k0 < K; k0 += BK) {
#pragma unroll
        for (int j = 0; j < LA; j++) {
            int idx = j * 256 + tid;
            int i = idx / BK, kk = idx % BK;
            int kg = k0 + kk;
            As[kk][i] = (kg < K) ? A[(size_t)(m0 + i) * lda + kg] : 0.f;
        }
#pragma unroll
        for (int j = 0; j < LB; j++) {
            int idx = j * 256 + tid;
            int i = idx / BK, kk = idx % BK;
            int kg = k0 + kk;
            Bs[kk][i] = (kg < K) ? B[(size_t)(n0 + i) * ldb + kg] : 0.f;
        }
        __syncthreads();
#pragma unroll
        for (int kk = 0; kk < BK; kk++) {
            float a[TM], b[TN];
#pragma unroll
            for (int i = 0; i < TM; i++) a[i] = As[kk][ty * TM + i];
#pragma unroll
            for (int j = 0; j < TN; j++) b[j] = Bs[kk][tx * TN + j];
#pragma unroll
            for (int i = 0; i < TM; i++)
#pragma unroll
                for (int j = 0; j < TN; j++)
                    acc[i][j] = fmaf(a[i], b[j], acc[i][j]);
        }
        __syncthreads();
    }

#pragma unroll
    for (int i = 0; i < TM; i++) {
        int m = m0 + ty * TM + i;
#pragma unroll
        for (int j = 0; j < TN; j++) {
            int n = n0 + tx * TN + j;
            float val = acc[i][j];
            if (bias) val += bias[n];
            if (ACT == 1) val = tanhf(val);
            if (OUTBF)
                ((ushort*)Cv)[(size_t)m * ldc + n] = f2bf(val);
            else
                ((float*)Cv)[(size_t)m * ldc + n] = val;
        }
    }
}

// ---------------- bf16 MFMA GEMM: C[m,n] = sum_k A[m,k]*B[n,k] ----------------
// A: M x K bf16 row-major, B: N x K bf16 row-major, C: f32 row-major (ldc)
// Tile 128x128, BK=32, 4 waves (2x2), each wave 64x64 = 4x4 fragments 16x16.
__global__ __launch_bounds__(256) void gemm_mfma_nt(
    const ushort* __restrict__ A,
    const ushort* __restrict__ B,
    float* __restrict__ C, int ldc, int K)
{
    __shared__ ushort As[128][40];   // +8 pad: 80B row stride, 16B aligned, conflict-light
    __shared__ ushort Bs[128][40];
    const int tid  = threadIdx.x;
    const int lane = tid & 63;
    const int wave = tid >> 6;
    const int wm = (wave >> 1) * 64;
    const int wn = (wave & 1) * 64;
    const int m0 = blockIdx.y * 128, n0 = blockIdx.x * 128;

    f32x4 acc[4][4] = {};

    const int r0  = tid >> 2;      // 0..63
    const int ch0 = tid & 3;       // 8-bf16 chunk within a 32-wide row

    for (int k0 = 0; k0 < K; k0 += 32) {
        uint4 a0 = *(const uint4*)&A[(size_t)(m0 + r0)      * K + k0 + ch0 * 8];
        uint4 a1 = *(const uint4*)&A[(size_t)(m0 + r0 + 64) * K + k0 + ch0 * 8];
        uint4 b0 = *(const uint4*)&B[(size_t)(n0 + r0)      * K + k0 + ch0 * 8];
        uint4 b1 = *(const uint4*)&B[(size_t)(n0 + r0 + 64) * K + k0 + ch0 * 8];
        *(uint4*)&As[r0][ch0 * 8]      = a0;
        *(uint4*)&As[r0 + 64][ch0 * 8] = a1;
        *(uint4*)&Bs[r0][ch0 * 8]      = b0;
        *(uint4*)&Bs[r0 + 64][ch0 * 8] = b1;
        __syncthreads();

        const int ko = (lane >> 4) * 8;   // k-offset of this lane's fragment slice
        bf16x8 af[4], bfr[4];
#pragma unroll
        for (int i = 0; i < 4; i++)
            af[i] = __builtin_bit_cast(bf16x8, *(const uint4*)&As[wm + i * 16 + (lane & 15)][ko]);
#pragma unroll
        for (int j = 0; j < 4; j++)
            bfr[j] = __builtin_bit_cast(bf16x8, *(const uint4*)&Bs[wn + j * 16 + (lane & 15)][ko]);
#pragma unroll
        for (int i = 0; i < 4; i++)
#pragma unroll
            for (int j = 0; j < 4; j++)
                acc[i][j] = __builtin_amdgcn_mfma_f32_16x16x32_bf16(af[i], bfr[j], acc[i][j], 0, 0, 0);
        __syncthreads();
    }

    // C/D layout: col = lane&15, row = (lane>>4)*4 + reg
#pragma unroll
    for (int i = 0; i < 4; i++) {
#pragma unroll
        for (int j = 0; j < 4; j++) {
            int row = m0 + wm + i * 16 + (lane >> 4) * 4;
            int col = n0 + wn + j * 16 + (lane & 15);
#pragma unroll
            for (int r = 0; r < 4; r++)
                C[(size_t)(row + r) * ldc + col] = acc[i][j][r];
        }
    }
}

// ---------------- f32 -> bf16 weight conversion (er_w ++ ad_w) ----------------
__global__ void convw_kernel(const float* __restrict__ er, const float* __restrict__ ad,
                             ushort* __restrict__ out) {
    int idx = blockIdx.x * 256 + threadIdx.x;   // 2*524288 total
    float v = (idx < D_ * H_ * H_) ? er[idx] : ad[idx - D_ * H_ * H_];
    out[idx] = f2bf(v);
}

// ---------------- softmax over rows of 128 (w) ----------------
__global__ void softmax128_kernel(float* __restrict__ w) {
    int n = blockIdx.x;
    int t = threadIdx.x;  // 64
    float v0 = w[n * M_ + t], v1 = w[n * M_ + 64 + t];
    float mx = fmaxf(v0, v1);
#pragma unroll
    for (int off = 32; off; off >>= 1) mx = fmaxf(mx, __shfl_xor(mx, off));
    float e0 = expf(v0 - mx), e1 = expf(v1 - mx);
    float s = e0 + e1;
#pragma unroll
    for (int off = 32; off; off >>= 1) s += __shfl_xor(s, off);
    float inv = 1.f / s;
    w[n * M_ + t] = e0 * inv;
    w[n * M_ + 64 + t] = e1 * inv;
}

// ---------------- w2 = softmax(k @ kw2_w.T + kw2_b) over D=8 ----------------
__global__ void w2_kernel(const float* __restrict__ k, const float* __restrict__ kw2_w,
                          const float* __restrict__ kw2_b, float* __restrict__ w2) {
    int t = threadIdx.x;               // 64 = 8 samples x 8 experts
    int n = blockIdx.x * 8 + (t >> 3);
    int d = t & 7;
    const float* kr = k + (size_t)n * H_;
    const float* wr = kw2_w + (size_t)d * H_;
    float acc = kw2_b[d];
    for (int h = 0; h < H_; h += 4)
        acc += kr[h] * wr[h] + kr[h + 1] * wr[h + 1] + kr[h + 2] * wr[h + 2] + kr[h + 3] * wr[h + 3];
    float mx = acc;
#pragma unroll
    for (int off = 1; off < 8; off <<= 1) mx = fmaxf(mx, __shfl_xor(mx, off));
    float e = expf(acc - mx);
    float s = e;
#pragma unroll
    for (int off = 1; off < 8; off <<= 1) s += __shfl_xor(s, off);
    w2[(size_t)n * D_ + d] = e / s;
}

// ---------------- gate: out = act(sum_d w2[n,d]*(t[n,d*H+o] + bias[d,o])) ----------------
template<int ACT>  // 0 = sigmoid, 1 = tanh
__global__ void gate_kernel(const float* __restrict__ t, const float* __restrict__ w2,
                            const float* __restrict__ bias, float* __restrict__ out) {
    int idx = blockIdx.x * 256 + threadIdx.x;  // N*H
    int n = idx >> 8;
    int o = idx & 255;
    const float* w2r = w2 + (size_t)n * D_;
    float acc = 0.f;
#pragma unroll
    for (int d = 0; d < D_; d++)
        acc += w2r[d] * (t[(size_t)n * (D_ * H_) + d * H_ + o] + bias[d * H_ + o]);
    out[idx] = (ACT == 0) ? 1.f / (1.f + expf(-acc)) : tanhf(acc);
}

// ---------------- fused memory pass: r = sum_m mem*w ; mem_out = mem*(1-w*e)+w*a ----
__global__ __launch_bounds__(256) void mem_kernel(
    const float* __restrict__ mem_in, const float* __restrict__ w,
    const float* __restrict__ e, const float* __restrict__ a,
    float* __restrict__ mem_out, float* __restrict__ r)
{
    __shared__ float wl[M_];
    int n = blockIdx.x;
    int t = threadIdx.x;
    if (t < M_) wl[t] = w[(size_t)n * M_ + t];
    __syncthreads();
    int wave = t >> 6, lane = t & 63;
    float w0 = wl[lane * 2], w1 = wl[lane * 2 + 1];
    const float2* min2 = (const float2*)(mem_in + (size_t)n * H_ * M_);
    float2* mout2 = (float2*)(mem_out + (size_t)n * H_ * M_);
    for (int h = wave; h < H_; h += 4) {
        float2 mv = min2[h * 64 + lane];
        float eh = e[(size_t)n * H_ + h], ah = a[(size_t)n * H_ + h];
        float2 nv;
        nv.x = mv.x * (1.f - w0 * eh) + w0 * ah;
        nv.y = mv.y * (1.f - w1 * eh) + w1 * ah;
        mout2[h * 64 + lane] = nv;
        float racc = mv.x * w0 + mv.y * w1;
#pragma unroll
        for (int off = 32; off; off >>= 1) racc += __shfl_xor(racc, off);
        if (lane == 0) r[(size_t)n * H_ + h] = racc;
    }
}

// ---------------- kr = concat(k, r) ----------------
__global__ void concat_kernel(const float* __restrict__ k, const float* __restrict__ r,
                              float* __restrict__ kr) {
    int idx = blockIdx.x * 256 + threadIdx.x;
    int n = idx >> 9, c = idx & 511;
    kr[idx] = (c < H_) ? k[(size_t)n * H_ + c] : r[(size_t)n * H_ + c - H_];
}

// ---------------- y[n] = f[n,:] . out_w + out_b ----------------
__global__ void y_kernel(const float* __restrict__ f, const float* __restrict__ out_w,
                         const float* __restrict__ out_b, float* __restrict__ y) {
    int n = blockIdx.x, t = threadIdx.x;  // 64
    float acc = 0.f;
#pragma unroll
    for (int j = 0; j < 4; j++) acc += f[(size_t)n * H_ + t + j * 64] * out_w[t + j * 64];
#pragma unroll
    for (int off = 32; off; off >>= 1) acc += __shfl_xor(acc, off);
    if (t == 0) y[n] = acc + out_b[0];
}

extern "C" void kernel_launch(void* const* d_in, const int* in_sizes, int n_in,
                              void* d_out, int out_size, void* d_ws, size_t ws_size,
                              hipStream_t stream) {
    const float* x      = (const float*)d_in[0];
    const float* mem_in = (const float*)d_in[1];
    const float* ke_w   = (const float*)d_in[2];
    const float* ke_b   = (const float*)d_in[3];
    const float* km_w   = (const float*)d_in[4];
    const float* km_b   = (const float*)d_in[5];
    const float* kw2_w  = (const float*)d_in[6];
    const float* kw2_b  = (const float*)d_in[7];
    const float* sum_w  = (const float*)d_in[8];
    const float* sum_b  = (const float*)d_in[9];
    const float* out_w  = (const float*)d_in[10];
    const float* out_b  = (const float*)d_in[11];
    const float* ve_w   = (const float*)d_in[12];
    const float* ve_b   = (const float*)d_in[13];
    const float* er_w   = (const float*)d_in[14];
    const float* er_b   = (const float*)d_in[15];
    const float* ad_w   = (const float*)d_in[16];
    const float* ad_b   = (const float*)d_in[17];

    float* y_out   = (float*)d_out;
    float* mem_out = (float*)d_out + N_;  // y (2048) then memory

    // ---- workspace layout (floats), with lifetime-based aliasing ----
    float* ws = (float*)d_ws;
    float* tbuf = ws;                            // 2048*2048 = 4194304 (expert GEMM out)
    float* q    = ws;                            // alias: dead before tbuf written
    float* kr   = ws;                            // alias: live after tbuf dead (1048576)
    float* f    = ws + 1048576;                  // alias: within tbuf region (524288)
    size_t off = 4194304;
    float* kb   = ws + off; off += (size_t)N_ * H_;        // 524288
    float* w    = ws + off; off += (size_t)N_ * M_;        // 262144
    float* w2   = ws + off; off += (size_t)N_ * D_;        // 16384
    float* e    = ws + off; off += (size_t)N_ * H_;        // 524288
    float* a    = ws + off; off += (size_t)N_ * H_;        // 524288
    float* r    = ws + off; off += (size_t)N_ * H_;        // 524288
    ushort* v_bf = (ushort*)(ws + off); off += (size_t)N_ * H_ / 2;      // 524288 ushort
    ushort* wcat = (ushort*)(ws + off); off += (size_t)2 * D_ * H_ * H_ / 2; // 1048576 ushort

    // 1. q = sum of halves
    q_kernel<<<(N_ * C_ + 255) / 256, 256, 0, stream>>>(x, q);
    // 2. k = q @ ke_w.T + ke_b   (2048 x 256, K=200)
    gemm_nt<64, 64, 16, 4, 4, 0, 0><<<dim3(H_ / 64, N_ / 64), 256, 0, stream>>>(
        q, C_, ke_w, C_, ke_b, kb, H_, N_, H_, C_);
    // 3. w logits = k @ km_w.T + km_b  (2048 x 128, K=256)
    gemm_nt<64, 64, 16, 4, 4, 0, 0><<<dim3(M_ / 64, N_ / 64), 256, 0, stream>>>(
        kb, H_, km_w, H_, km_b, w, M_, N_, M_, H_);
    // 4. softmax rows of 128
    softmax128_kernel<<<N_, 64, 0, stream>>>(w);
    // 5. w2 logits + softmax over D=8
    w2_kernel<<<N_ / 8, 64, 0, stream>>>(kb, kw2_w, kw2_b, w2);
    // 6. v = x @ ve_w.T + ve_b  (K=400) -> bf16 out
    gemm_nt<64, 64, 16, 4, 4, 0, 1><<<dim3(H_ / 64, N_ / 64), 256, 0, stream>>>(
        x, IN_, ve_w, IN_, ve_b, v_bf, H_, N_, H_, IN_);
    // 7. weights f32 -> bf16 (er ++ ad)
    convw_kernel<<<(2 * D_ * H_ * H_) / 256, 256, 0, stream>>>(er_w, ad_w, wcat);
    // 8. t_er = v @ er_w.T (bf16 MFMA, 2048x2048x256)
    gemm_mfma_nt<<<dim3(16, 16), 256, 0, stream>>>(v_bf, wcat, tbuf, D_ * H_, H_);
    // 9. e = sigmoid(sum_d w2*(t+er_b))
    gate_kernel<0><<<(N_ * H_) / 256, 256, 0, stream>>>(tbuf, w2, er_b, e);
    // 10. t_ad = v @ ad_w.T
    gemm_mfma_nt<<<dim3(16, 16), 256, 0, stream>>>(v_bf, wcat + (size_t)D_ * H_ * H_, tbuf, D_ * H_, H_);
    // 11. a = tanh(sum_d w2*(t+ad_b))
    gate_kernel<1><<<(N_ * H_) / 256, 256, 0, stream>>>(tbuf, w2, ad_b, a);
    // 12. fused memory read + update
    mem_kernel<<<N_, 256, 0, stream>>>(mem_in, w, e, a, mem_out, r);
    // 13. kr = [k, r]
    concat_kernel<<<(N_ * 2 * H_) / 256, 256, 0, stream>>>(kb, r, kr);
    // 14. f = tanh(kr @ sum_w.T + sum_b)  (K=512)
    gemm_nt<64, 64, 16, 4, 4, 1, 0><<<dim3(H_ / 64, N_ / 64), 256, 0, stream>>>(
        kr, 2 * H_, sum_w, 2 * H_, sum_b, f, H_, N_, H_, 2 * H_);
    // 15. y
    y_kernel<<<N_, 64, 0, stream>>>(f, out_w, out_b, y_out);
}

// Round 3
// 226.833 us; speedup vs baseline: 2.2230x; 1.6044x over previous
//
#include <hip/hip_runtime.h>
#include <math.h>

#define N_  2048
#define IN_ 400
#define C_  200
#define H_  256
#define M_  128
#define D_  8

#define KQ   224   // C_=200 padded to x32
#define KX   416   // IN_=400 padded to x32
#define KBIG 2112  // 2048 data + 8 bias + 56 pad (66*32)
#define KS   512   // [k | r]

typedef __bf16 bf16x8 __attribute__((ext_vector_type(8)));
typedef float  f32x4  __attribute__((ext_vector_type(4)));

__device__ __forceinline__ ushort f2bf(float x) { __bf16 b = (__bf16)x; return __builtin_bit_cast(ushort, b); }
__device__ __forceinline__ float  bf2f(ushort u) { unsigned v = ((unsigned)u) << 16; return __builtin_bit_cast(float, v); }

// ---------------- prep: x_bf (N x 416), q_bf (N x 224) ----------------
__global__ void prep_kernel(const float* __restrict__ x,
                            ushort* __restrict__ x_bf, ushort* __restrict__ q_bf) {
    int idx = blockIdx.x * 256 + threadIdx.x;      // N*KX = 851968, exact grid
    int n = idx / KX, c = idx % KX;
    float xv = (c < IN_) ? x[n * IN_ + c] : 0.f;
    x_bf[idx] = f2bf(xv);
    if (c < KQ) {
        float qv = (c < C_) ? x[n * IN_ + c] + x[n * IN_ + C_ + c] : 0.f;
        q_bf[n * KQ + c] = f2bf(qv);
    }
}

// ---------------- weight conversion: ke(256x224) ve(256x416) sum(256x512) km(128x256) ----
#define WC_KE (256 * KQ)                 // 57344
#define WC_VE (WC_KE + 256 * KX)         // 163840
#define WC_SW (WC_VE + 256 * 512)        // 294912
#define WC_KM (WC_SW + 128 * 256)        // 327680
__global__ void wconv_kernel(const float* __restrict__ ke, const float* __restrict__ ve,
                             const float* __restrict__ sw, const float* __restrict__ km,
                             ushort* __restrict__ out) {
    int idx = blockIdx.x * 256 + threadIdx.x;  // 327680 total, exact grid
    float val;
    if (idx < WC_KE)      { int r = idx / KQ, c = idx % KQ; val = (c < C_) ? ke[r * C_ + c] : 0.f; }
    else if (idx < WC_VE) { int j = idx - WC_KE; int r = j / KX, c = j % KX; val = (c < IN_) ? ve[r * IN_ + c] : 0.f; }
    else if (idx < WC_SW) { val = sw[idx - WC_VE]; }
    else                  { val = km[idx - WC_SW]; }
    out[idx] = f2bf(val);
}

// ---------------- Wcat repack: [er | ad] -> (512 x 2112) bf16, bias in cols 2048..2055 ----
__global__ void wcat_kernel(const float* __restrict__ er_w, const float* __restrict__ er_b,
                            const float* __restrict__ ad_w, const float* __restrict__ ad_b,
                            ushort* __restrict__ out) {
    int idx = blockIdx.x * 256 + threadIdx.x;  // 512 * 528 = 270336, exact grid
    int o = idx / (KBIG / 4), g = idx % (KBIG / 4);
    int c0 = g * 4;
    const float* Wsrc = (o < 256) ? er_w : ad_w;
    const float* bsrc = (o < 256) ? er_b : ad_b;
    int oo = o & 255;
    ushort pk[4];
#pragma unroll
    for (int j = 0; j < 4; j++) {
        int c = c0 + j;
        float val = 0.f;
        if (c < 2048)      { int d = c >> 8, i = c & 255; val = Wsrc[(size_t)(d * 256 + oo) * 256 + i]; }
        else if (c < 2056) { int d = c - 2048; val = bsrc[d * 256 + oo]; }
        pk[j] = f2bf(val);
    }
    *(ushort4*)&out[(size_t)o * KBIG + c0] = *(ushort4*)pk;
}

// ---------------- vw fill: vw[n, d*256+i] = w2[n,d]*v[n,i]; cols 2048..2055 = w2 ----
__global__ void vwfill_kernel(const float* __restrict__ v, const float* __restrict__ w2,
                              ushort* __restrict__ vw) {
    int idx = blockIdx.x * 256 + threadIdx.x;  // 2048 * 528 = 1081344, exact grid
    int n = idx / (KBIG / 4), g = idx % (KBIG / 4);
    int c0 = g * 4;
    ushort pk[4];
#pragma unroll
    for (int j = 0; j < 4; j++) {
        int c = c0 + j;
        float val = 0.f;
        if (c < 2048)      { int d = c >> 8, i = c & 255; val = w2[n * D_ + d] * v[n * H_ + i]; }
        else if (c < 2056) { val = w2[n * D_ + (c - 2048)]; }
        pk[j] = f2bf(val);
    }
    *(ushort4*)&vw[(size_t)n * KBIG + c0] = *(ushort4*)pk;
}

// ---------------- unified bf16 MFMA NT GEMM ----------------
// C[m,n] = act(sum_k A[m,k]*B[n,k] + bias[n]); tile BM=128 x BN=64, 4 waves (2x2),
// wave tile 64x32 -> 4x2 fragments of 16x16, BK=32.
// ACT: 0 none, 1 tanh. OUTBF: 0 f32, 1 bf16.
// gridDim.z splits K: k in [z*ksplit, (z+1)*ksplit), C += z*csplit elements.
template<int ACT, int OUTBF>
__global__ __launch_bounds__(256) void gemm_mfma(
    const ushort* __restrict__ A, int lda,
    const ushort* __restrict__ B, int ldb,
    const float* __restrict__ bias,
    void* __restrict__ Cv, int ldc, size_t csplit, int ksplit)
{
    constexpr int BM = 128, BN = 64;
    __shared__ ushort As[BM][40];
    __shared__ ushort Bs[BN][40];
    const int tid = threadIdx.x, lane = tid & 63, wave = tid >> 6;
    const int wm = (wave >> 1) * 64, wn = (wave & 1) * 32;
    const int m0 = blockIdx.y * BM, n0 = blockIdx.x * BN;
    const int kFrom = blockIdx.z * ksplit, kTo = kFrom + ksplit;

    f32x4 acc[4][2] = {};

    const int sr = tid >> 2;          // 0..63
    const int sc = (tid & 3) * 8;     // 0,8,16,24

    for (int k0 = kFrom; k0 < kTo; k0 += 32) {
        uint4 a0 = *(const uint4*)&A[(size_t)(m0 + sr) * lda + k0 + sc];
        uint4 a1 = *(const uint4*)&A[(size_t)(m0 + sr + 64) * lda + k0 + sc];
        uint4 b0 = *(const uint4*)&B[(size_t)(n0 + sr) * ldb + k0 + sc];
        *(uint4*)&As[sr][sc] = a0;
        *(uint4*)&As[sr + 64][sc] = a1;
        *(uint4*)&Bs[sr][sc] = b0;
        __syncthreads();

        const int ko = (lane >> 4) * 8;
        bf16x8 af[4], bfr[2];
#pragma unroll
        for (int i = 0; i < 4; i++)
            af[i] = __builtin_bit_cast(bf16x8, *(const uint4*)&As[wm + i * 16 + (lane & 15)][ko]);
#pragma unroll
        for (int j = 0; j < 2; j++)
            bfr[j] = __builtin_bit_cast(bf16x8, *(const uint4*)&Bs[wn + j * 16 + (lane & 15)][ko]);
#pragma unroll
        for (int i = 0; i < 4; i++)
#pragma unroll
            for (int j = 0; j < 2; j++)
                acc[i][j] = __builtin_amdgcn_mfma_f32_16x16x32_bf16(af[i], bfr[j], acc[i][j], 0, 0, 0);
        __syncthreads();
    }

    float* Cf = (float*)Cv + blockIdx.z * csplit;
    ushort* Cb = (ushort*)Cv + blockIdx.z * csplit;
#pragma unroll
    for (int i = 0; i < 4; i++) {
#pragma unroll
        for (int j = 0; j < 2; j++) {
            int row = m0 + wm + i * 16 + (lane >> 4) * 4;
            int col = n0 + wn + j * 16 + (lane & 15);
#pragma unroll
            for (int r = 0; r < 4; r++) {
                float val = acc[i][j][r];
                if (bias) val += bias[col];
                if (ACT == 1) val = tanhf(val);
                if (OUTBF) Cb[(size_t)(row + r) * ldc + col] = f2bf(val);
                else       Cf[(size_t)(row + r) * ldc + col] = val;
            }
        }
    }
}

// ---------------- w2 = softmax over D=8 of k @ kw2_w.T + kw2_b (k from kr bf16) ----
__global__ void w2_kernel(const ushort* __restrict__ kr, const float* __restrict__ kw2_w,
                          const float* __restrict__ kw2_b, float* __restrict__ w2) {
    int t = threadIdx.x;               // 64 = 8 samples x 8 experts
    int n = blockIdx.x * 8 + (t >> 3);
    int d = t & 7;
    const ushort* krow = kr + (size_t)n * KS;
    const float* wr = kw2_w + d * H_;
    float acc = kw2_b[d];
    for (int h = 0; h < H_; h += 4)
        acc += bf2f(krow[h]) * wr[h] + bf2f(krow[h + 1]) * wr[h + 1]
             + bf2f(krow[h + 2]) * wr[h + 2] + bf2f(krow[h + 3]) * wr[h + 3];
    float mx = acc;
#pragma unroll
    for (int off = 1; off < 8; off <<= 1) mx = fmaxf(mx, __shfl_xor(mx, off));
    float e = expf(acc - mx);
    float s = e;
#pragma unroll
    for (int off = 1; off < 8; off <<= 1) s += __shfl_xor(s, off);
    w2[(size_t)n * D_ + d] = e / s;
}

// ---------------- softmax over rows of 128 (in place) ----------------
__global__ void softmax128_kernel(float* __restrict__ w) {
    int n = blockIdx.x;
    int t = threadIdx.x;  // 64
    float v0 = w[n * M_ + t], v1 = w[n * M_ + 64 + t];
    float mx = fmaxf(v0, v1);
#pragma unroll
    for (int off = 32; off; off >>= 1) mx = fmaxf(mx, __shfl_xor(mx, off));
    float e0 = expf(v0 - mx), e1 = expf(v1 - mx);
    float s = e0 + e1;
#pragma unroll
    for (int off = 32; off; off >>= 1) s += __shfl_xor(s, off);
    float inv = 1.f / s;
    w[n * M_ + t] = e0 * inv;
    w[n * M_ + 64 + t] = e1 * inv;
}

// ---------------- fused memory pass ----------------
// e = sigmoid(p0+p1) cols 0..255; a = tanh(p0+p1) cols 256..511 (computed in LDS);
// r = sum_m mem*w -> kr[:,256+h] bf16 ; mem_out = mem*(1-w*e)+w*a
__global__ __launch_bounds__(256) void mem_kernel(
    const float* __restrict__ mem_in, const float* __restrict__ w,
    const float* __restrict__ p0, const float* __restrict__ p1,
    float* __restrict__ mem_out, ushort* __restrict__ kr)
{
    __shared__ float wl[M_];
    __shared__ float el[H_], al[H_];
    int n = blockIdx.x;
    int t = threadIdx.x;
    if (t < M_) wl[t] = w[(size_t)n * M_ + t];
    {
        float s0 = p0[(size_t)n * 512 + t] + p1[(size_t)n * 512 + t];
        float s1 = p0[(size_t)n * 512 + 256 + t] + p1[(size_t)n * 512 + 256 + t];
        el[t] = 1.f / (1.f + expf(-s0));
        al[t] = tanhf(s1);
    }
    __syncthreads();
    int wave = t >> 6, lane = t & 63;
    int half = lane >> 5, l32 = lane & 31;
    const float4* min4 = (const float4*)(mem_in + (size_t)n * H_ * M_);
    float4* mout4 = (float4*)(mem_out + (size_t)n * H_ * M_);
    float4 wv = ((const float4*)wl)[l32];
    for (int h = wave * 2 + half; h < H_; h += 8) {
        float4 mv = min4[h * 32 + l32];
        float eh = el[h], ah = al[h];
        float4 nv;
        nv.x = mv.x * (1.f - wv.x * eh) + wv.x * ah;
        nv.y = mv.y * (1.f - wv.y * eh) + wv.y * ah;
        nv.z = mv.z * (1.f - wv.z * eh) + wv.z * ah;
        nv.w = mv.w * (1.f - wv.w * eh) + wv.w * ah;
        mout4[h * 32 + l32] = nv;
        float racc = mv.x * wv.x + mv.y * wv.y + mv.z * wv.z + mv.w * wv.w;
#pragma unroll
        for (int off = 1; off < 32; off <<= 1) racc += __shfl_xor(racc, off);
        if (l32 == 0) kr[(size_t)n * KS + H_ + h] = f2bf(racc);
    }
}

// ---------------- y[n] = f[n,:] . out_w + out_b ----------------
__global__ void y_kernel(const float* __restrict__ f, const float* __restrict__ out_w,
                         const float* __restrict__ out_b, float* __restrict__ y) {
    int n = blockIdx.x, t = threadIdx.x;  // 64
    float acc = 0.f;
#pragma unroll
    for (int j = 0; j < 4; j++) acc += f[(size_t)n * H_ + t + j * 64] * out_w[t + j * 64];
#pragma unroll
    for (int off = 32; off; off >>= 1) acc += __shfl_xor(acc, off);
    if (t == 0) y[n] = acc + out_b[0];
}

extern "C" void kernel_launch(void* const* d_in, const int* in_sizes, int n_in,
                              void* d_out, int out_size, void* d_ws, size_t ws_size,
                              hipStream_t stream) {
    const float* x      = (const float*)d_in[0];
    const float* mem_in = (const float*)d_in[1];
    const float* ke_w   = (const float*)d_in[2];
    const float* ke_b   = (const float*)d_in[3];
    const float* km_w   = (const float*)d_in[4];
    const float* km_b   = (const float*)d_in[5];
    const float* kw2_w  = (const float*)d_in[6];
    const float* kw2_b  = (const float*)d_in[7];
    const float* sum_w  = (const float*)d_in[8];
    const float* sum_b  = (const float*)d_in[9];
    const float* out_w  = (const float*)d_in[10];
    const float* out_b  = (const float*)d_in[11];
    const float* ve_w   = (const float*)d_in[12];
    const float* ve_b   = (const float*)d_in[13];
    const float* er_w   = (const float*)d_in[14];
    const float* er_b   = (const float*)d_in[15];
    const float* ad_w   = (const float*)d_in[16];
    const float* ad_b   = (const float*)d_in[17];

    float* y_out   = (float*)d_out;
    float* mem_out = (float*)d_out + N_;

    // ---- workspace layout (float units, all offsets 16B-aligned) ----
    float* ws = (float*)d_ws;
    size_t o = 0;
    float*  parts  = ws + o;            o += (size_t)2 * N_ * 512;       // 2 x (N x 512)
    ushort* vw     = (ushort*)(ws + o); o += (size_t)N_ * KBIG / 2;
    ushort* Wcat   = (ushort*)(ws + o); o += (size_t)512 * KBIG / 2;
    ushort* kr     = (ushort*)(ws + o); o += (size_t)N_ * KS / 2;
    ushort* x_bf   = (ushort*)(ws + o); o += (size_t)N_ * KX / 2;
    ushort* q_bf   = (ushort*)(ws + o); o += (size_t)N_ * KQ / 2;
    ushort* ke_bf  = (ushort*)(ws + o); o += (size_t)256 * KQ / 2;
    ushort* ve_bf  = (ushort*)(ws + o); o += (size_t)256 * KX / 2;
    ushort* sum_bf = (ushort*)(ws + o); o += (size_t)256 * 512 / 2;
    ushort* km_bf  = (ushort*)(ws + o); o += (size_t)128 * 256 / 2;
    float*  v      = ws + o;            o += (size_t)N_ * H_;
    float*  w      = ws + o;            o += (size_t)N_ * M_;
    float*  w2     = ws + o;            o += (size_t)N_ * D_;
    float*  f      = ws + o;            o += (size_t)N_ * H_;

    // 1. prep: x_bf, q_bf
    prep_kernel<<<(N_ * KX) / 256, 256, 0, stream>>>(x, x_bf, q_bf);
    // 2. weight conversions (ke/ve/sum/km, contiguous out)
    wconv_kernel<<<WC_KM / 256, 256, 0, stream>>>(ke_w, ve_w, sum_w, km_w, ke_bf);
    // 3. Wcat repack (er|ad + biases)
    wcat_kernel<<<(512 * KBIG / 4) / 256, 256, 0, stream>>>(er_w, er_b, ad_w, ad_b, Wcat);
    // 4. k = q @ ke_w.T + ke_b -> kr[:, 0:256] bf16
    gemm_mfma<0, 1><<<dim3(H_ / 64, N_ / 128, 1), 256, 0, stream>>>(
        q_bf, KQ, ke_bf, KQ, ke_b, kr, KS, 0, KQ);
    // 5. w2 = softmax_D(k @ kw2_w.T + kw2_b)
    w2_kernel<<<N_ / 8, 64, 0, stream>>>(kr, kw2_w, kw2_b, w2);
    // 6. w logits = k @ km_w.T + km_b
    gemm_mfma<0, 0><<<dim3(M_ / 64, N_ / 128, 1), 256, 0, stream>>>(
        kr, KS, km_bf, H_, km_b, w, M_, 0, H_);
    // 7. softmax rows of 128
    softmax128_kernel<<<N_, 64, 0, stream>>>(w);
    // 8. v = x @ ve_w.T + ve_b (f32 out)
    gemm_mfma<0, 0><<<dim3(H_ / 64, N_ / 128, 1), 256, 0, stream>>>(
        x_bf, KX, ve_bf, KX, ve_b, v, H_, 0, KX);
    // 9. vw = w2 (x) v  (bf16, K-major d*256+i, bias cols)
    vwfill_kernel<<<(N_ * KBIG / 4) / 256, 256, 0, stream>>>(v, w2, vw);
    // 10. big fused expert GEMM: parts[z] = vw @ Wcat.T (K split in 2)
    gemm_mfma<0, 0><<<dim3(512 / 64, N_ / 128, 2), 256, 0, stream>>>(
        vw, KBIG, Wcat, KBIG, nullptr, parts, 512, (size_t)N_ * 512, KBIG / 2);
    // 11. fused memory: act(p0+p1) -> e,a ; read-reduce r -> kr[:,256:]; erase/add -> mem_out
    mem_kernel<<<N_, 256, 0, stream>>>(mem_in, w, parts, parts + (size_t)N_ * 512, mem_out, kr);
    // 12. f = tanh(kr @ sum_w.T + sum_b)
    gemm_mfma<1, 0><<<dim3(H_ / 64, N_ / 128, 1), 256, 0, stream>>>(
        kr, KS, sum_bf, KS, sum_b, f, H_, 0, KS);
    // 13. y
    y_kernel<<<N_, 64, 0, stream>>>(f, out_w, out_b, y_out);
}